// Round 1
// baseline (70.048 us; speedup 1.0000x reference)
//
#include <hip/hip_runtime.h>

// out[o,k,h,m] = sum_{i,j} p[o,i,(h-1)%14, m+j] * w[i,k,j]
// p[q]=0 for q in {0,15}; p[q] = x[o,i,n,(q-2)%14] for q in [1,14], n=(h-1)%14
//
// Grid: (kt=8, h=14, o=2) = 224 blocks. Block: 448 threads = 14 m * 32 kk.
// LDS: padded rows xs[i][16] holding p[o,i,n,0..15]. Tap read = xs[i*16+m+j].

#define BLOCK_THREADS 448

__global__ __launch_bounds__(BLOCK_THREADS) void shiftconv_kernel(
    const float* __restrict__ x,   // (2,256,14,14) flat
    const float* __restrict__ w,   // (256,256,3) flat
    float* __restrict__ out)       // (2,256,14,14) flat
{
    __shared__ float xs[256 * 16];   // 16 KB, padded p rows

    const int kt = blockIdx.x;       // 0..7  (k tile of 32)
    const int h  = blockIdx.y;       // 0..13
    const int o  = blockIdx.z;       // 0..1
    const int t  = threadIdx.x;      // 0..447
    const int n  = (h + 13) % 14;    // source H row after final roll

    // ---- stage x[o, :, n, :] into padded LDS rows ----
    // source element (i, ww) -> xs[i*16 + q], q = ww+2 (ww<=12) else 1
    // zeros at q=0 and q=15
    for (int e = t; e < 512; e += BLOCK_THREADS) {
        int i = e >> 1;
        xs[i * 16 + (e & 1) * 15] = 0.0f;
    }
    for (int e = t; e < 256 * 14; e += BLOCK_THREADS) {
        int i  = e / 14;
        int ww = e - i * 14;
        float v = x[((size_t)(o * 256 + i) * 14 + n) * 14 + ww];
        int q = (ww <= 12) ? (ww + 2) : 1;
        xs[i * 16 + q] = v;
    }
    __syncthreads();

    // ---- per-thread output ----
    const int kk = t & 31;           // fast: coalesced w loads
    const int m  = t >> 5;           // 0..13
    const int kglob = kt * 32 + kk;

    const float* wp = w + (size_t)kglob * 3;   // w[i,kglob,j], stride 768/i
    const float* xp = xs + m;                  // xs[i*16 + m + j]

    float acc = 0.0f;
#pragma unroll 8
    for (int i = 0; i < 256; ++i) {
        float w0 = wp[0];
        float w1 = wp[1];
        float w2 = wp[2];
        acc = fmaf(xp[0], w0, acc);
        acc = fmaf(xp[1], w1, acc);
        acc = fmaf(xp[2], w2, acc);
        wp += 768;
        xp += 16;
    }

    out[((size_t)(o * 256 + kglob) * 14 + h) * 14 + m] = acc;
}

extern "C" void kernel_launch(void* const* d_in, const int* in_sizes, int n_in,
                              void* d_out, int out_size, void* d_ws, size_t ws_size,
                              hipStream_t stream) {
    const float* x = (const float*)d_in[0];   // (1,512,14,14) = (2,256,14,14)
    const float* w = (const float*)d_in[1];   // (256,256,3)
    float* out = (float*)d_out;               // (1,512,14,14)

    dim3 grid(8, 14, 2);
    dim3 block(BLOCK_THREADS);
    shiftconv_kernel<<<grid, block, 0, stream>>>(x, w, out);
}